// Round 6
// baseline (144.660 us; speedup 1.0000x reference)
//
#include <hip/hip_runtime.h>

// B=4, T=4096, E=1024, H=64.
// out = Q @ M_b,  M_b = (1/32) * K_b^T V_b,  Q/K/V = idx@W + b   (linear attention:
// reference applies no mask/softmax). Scale folded into Wk/bk.
//
// R13: per-CU-traffic model. R7/R8/R10/R12 all ~42-47us because each moved ~1MB
// of L1-miss bytes per CU (B=WB 384KB x 2 blocks/CU dominates) at the ~22GB/s/CU
// cache-BW invariant. Fix: BM=64, grid 256 (1 block/CU, 16 waves = 4 row x 4 col
// frags) -> WB read ONCE per CU (384KB) + idx 256KB. B staged via global_load_lds
// (linear 12KB kk-slices, 4-slot), counted vmcnt(4) + raw s_barrier per kk (loads
// in flight ACROSS barriers, no drain). A direct per-wave (R12 addressing,
// capture-before-refill). Tail: Q via LDS; M from Lk/Lv -> 8-way atomicAdd.

typedef __attribute__((ext_vector_type(8))) short bf16x8;   // 8 bf16 = 4 VGPRs
typedef __attribute__((ext_vector_type(4))) float f32x4;    // MFMA C/D

#define MFMA16(a, b, c) __builtin_amdgcn_mfma_f32_16x16x32_bf16((a), (b), (c), 0, 0, 0)

__device__ __forceinline__ unsigned short f2bf(float f) {
    unsigned int u = __float_as_uint(f);
    u += 0x7fffu + ((u >> 16) & 1u);          // round-to-nearest-even
    return (unsigned short)(u >> 16);
}

__device__ __forceinline__ unsigned int cvtpk(float a, float b) {
    unsigned int r;                           // r = {bf16(a) lo, bf16(b) hi}
    asm("v_cvt_pk_bf16_f32 %0, %1, %2" : "=v"(r) : "v"(a), "v"(b));
    return r;
}

__device__ __forceinline__ bf16x8 cvt8(float4 lo, float4 hi) {
    union { unsigned int u[4]; bf16x8 v; } r;
    r.u[0] = cvtpk(lo.x, lo.y);
    r.u[1] = cvtpk(lo.z, lo.w);
    r.u[2] = cvtpk(hi.x, hi.y);
    r.u[3] = cvtpk(hi.z, hi.w);
    return r.v;
}

__device__ __forceinline__ void gll16(const unsigned short* g, unsigned short* l) {
    __builtin_amdgcn_global_load_lds(
        (const __attribute__((address_space(1))) void*)g,
        (__attribute__((address_space(3))) void*)l, 16, 0, 0);
}

// ---------------------------------------------------------------------------
// K0: weights -> MFMA-fragment order; zero the 8-way Mf accumulator (ws poisoned).
// Chunk t = (kk*12 + nt)*64 + lane holds 8 bf16:
//   W^T[n][k], n = nt*16 + (lane&15), k = kk*32 + (lane>>4)*8 + j.
// n<64 -> Wq, n<128 -> Wk * 1/32, else Wv.   (W is [k][h] in memory)
// kk-slice of WB = 12 KB contiguous (frag nt at offset nt*1KB) -> linear GLL copy.
__global__ void prep(const float* __restrict__ Wq, const float* __restrict__ Wk,
                     const float* __restrict__ Wv, unsigned short* __restrict__ WB,
                     float* __restrict__ Mf8) {
    int t = blockIdx.x * 256 + threadIdx.x;   // 96 blocks -> 24576 chunks
    for (int z = t; z < 131072; z += 24576) Mf8[z] = 0.f;   // 8*4*64*64 fp32
    int kki = t / 768;
    int rem = t - kki * 768;
    int nt = rem >> 6, lane = rem & 63;
    int n = nt * 16 + (lane & 15);
    int kb = kki * 32 + ((lane >> 4) * 8);
    int mm = n >> 6, h = n & 63;
    const float* W = (mm == 0) ? Wq : (mm == 1) ? Wk : Wv;
    float sc = (mm == 1) ? 0.03125f : 1.0f;
    bf16x8 v;
    #pragma unroll
    for (int j = 0; j < 8; j++) v[j] = (short)f2bf(W[(size_t)(kb + j) * 64 + h] * sc);
    *(bf16x8*)(WB + (size_t)t * 8) = v;
}

// ---------------------------------------------------------------------------
// K1: fused QKV projection + local K^T V contribution.
// Grid 256 x 1024 threads (16 waves: wr = w>>2 row-frag, wc = w&3 col-frag; frag
// f = wc + j*4, j in {Q,K,V}). Waves 0-11 also stage B kk-slices (wave w = frag w,
// 64 lanes x 16B = 1KB each) into 4-slot LDS ring. Per kk: vmcnt(4) [retires the
// 2-back stage], raw s_barrier, 3 ds_read_b128, issue stage kk+2 + A kk+2,
// cvt A, 3 MFMA. A-loads and stage-loads cross barriers (never drained).
__global__ __launch_bounds__(1024, 4) void qkv_m(
    const float* __restrict__ idx, const unsigned short* __restrict__ WB,
    const float* __restrict__ bq, const float* __restrict__ bk, const float* __restrict__ bv,
    unsigned short* __restrict__ Q, float* __restrict__ Mf8) {
    __shared__ unsigned short LDSB[4 * 6144];  // 48 KB: 4 x 12KB B slots; tail reuse

    const int tid = threadIdx.x, lane = tid & 63, w = tid >> 6;
    const int wr = w >> 2, wc = w & 3;
    const int r0 = blockIdx.x * 64;
    const bool stager = (w < 12);

    // A: lane covers row r0 + wr*16 + (lane&15), k-octet (lane>>4)*8
    const float* A0 = idx + (size_t)(r0 + wr * 16 + (lane & 15)) * 1024 + ((lane >> 4) * 8);
    // B stage addressing (shorts): slice kk at WB + kk*6144, wave w's 1KB at +w*512
    const int soff = w * 512 + lane * 8;

    // ---- prologue: stage slots 0,1; issue A(0) [even] and A(1) [odd] ----
    if (stager) {
        gll16(WB + 0 * 6144 + soff, LDSB + 0 * 6144 + soff);
        gll16(WB + 1 * 6144 + soff, LDSB + 1 * 6144 + soff);
    }
    float4 aE0 = *(const float4*)(A0 + 0),  aE1 = *(const float4*)(A0 + 4);
    float4 aO0 = *(const float4*)(A0 + 32), aO1 = *(const float4*)(A0 + 36);

    const f32x4 z4 = {0.f, 0.f, 0.f, 0.f};
    f32x4 acc[3] = {z4, z4, z4};

    for (int kk2 = 0; kk2 < 32; kk2 += 2) {
        // ======== even kk = kk2 ========
        {
            const int k = kk2;
            if (kk2 < 30) { asm volatile("s_waitcnt vmcnt(4)" ::: "memory"); }
            else          { asm volatile("s_waitcnt vmcnt(2)" ::: "memory"); }
            __builtin_amdgcn_s_barrier();
            __builtin_amdgcn_sched_barrier(0);
            const unsigned short* S = LDSB + (k & 3) * 6144;
            bf16x8 b0 = *(const bf16x8*)(S + (wc + 0) * 512 + lane * 8);
            bf16x8 b1 = *(const bf16x8*)(S + (wc + 4) * 512 + lane * 8);
            bf16x8 b2 = *(const bf16x8*)(S + (wc + 8) * 512 + lane * 8);
            float4 c0 = aE0, c1 = aE1;            // capture BEFORE refill
            if (kk2 < 30) {
                if (stager)
                    gll16(WB + (k + 2) * 6144 + soff, LDSB + ((k + 2) & 3) * 6144 + soff);
                const float* p = A0 + (k + 2) * 32;
                aE0 = *(const float4*)p; aE1 = *(const float4*)(p + 4);
            }
            bf16x8 a = cvt8(c0, c1);
            acc[0] = MFMA16(a, b0, acc[0]);
            acc[1] = MFMA16(a, b1, acc[1]);
            acc[2] = MFMA16(a, b2, acc[2]);
        }
        // ======== odd kk = kk2+1 ========
        {
            const int k = kk2 + 1;
            if (kk2 < 30) { asm volatile("s_waitcnt vmcnt(4)" ::: "memory"); }
            else          { asm volatile("s_waitcnt vmcnt(2)" ::: "memory"); }
            __builtin_amdgcn_s_barrier();
            __builtin_amdgcn_sched_barrier(0);
            const unsigned short* S = LDSB + (k & 3) * 6144;
            bf16x8 b0 = *(const bf16x8*)(S + (wc + 0) * 512 + lane * 8);
            bf16x8 b1 = *(const bf16x8*)(S + (wc + 4) * 512 + lane * 8);
            bf16x8 b2 = *(const bf16x8*)(S + (wc + 8) * 512 + lane * 8);
            float4 c0 = aO0, c1 = aO1;            // capture BEFORE refill
            if (kk2 < 30) {
                if (stager)
                    gll16(WB + (k + 2) * 6144 + soff, LDSB + ((k + 2) & 3) * 6144 + soff);
                const float* p = A0 + (k + 2) * 32;
                aO0 = *(const float4*)p; aO1 = *(const float4*)(p + 4);
            }
            bf16x8 a = cvt8(c0, c1);
            acc[0] = MFMA16(a, b0, acc[0]);
            acc[1] = MFMA16(a, b1, acc[1]);
            acc[2] = MFMA16(a, b2, acc[2]);
        }
    }

    // ---- tail: reuse LDSB as Lq/Lk/Lv [64][72] (16B-aligned rows) ----
    __syncthreads();                              // full drain before LDS reuse
    unsigned short* Lq = LDSB;                    // [row][col]
    unsigned short* Lk = LDSB + 4608;             // [h][t]
    unsigned short* Lv = LDSB + 9216;             // [h][t]
    {
        const int col   = wc * 16 + (lane & 15);
        const int rbase = wr * 16 + (lane >> 4) * 4;
        float b0v = bq[col], b1v = bk[col] * 0.03125f, b2v = bv[col];
        #pragma unroll
        for (int reg = 0; reg < 4; reg++) {
            int r = rbase + reg;
            Lq[r * 72 + col] = f2bf(acc[0][reg] + b0v);
            Lk[col * 72 + r] = f2bf(acc[1][reg] + b1v);
            Lv[col * 72 + r] = f2bf(acc[2][reg] + b2v);
        }
    }
    __syncthreads();

    // Q out: 64 rows x 64 cols bf16; thread -> (row = tid>>4, 4 cols)
    {
        int row = tid >> 4, c4 = (tid & 15) * 4;
        *(uint2*)(Q + (size_t)(r0 + row) * 64 + c4) = *(const uint2*)(Lq + row * 72 + c4);
    }

    // M contribution: M[h1][h2] += sum_t K[t][h1] V[t][h2]; wave (wr,wc) owns the
    // (h1-frag wr, h2-frag wc) 16x16 tile; K = t = 64 via two 16x16x32 MFMAs.
    {
        f32x4 accM = z4;
        #pragma unroll
        for (int ts = 0; ts < 64; ts += 32) {
            bf16x8 ka = *(const bf16x8*)(Lk + (wr * 16 + (lane & 15)) * 72 + ts + (lane >> 4) * 8);
            bf16x8 vb = *(const bf16x8*)(Lv + (wc * 16 + (lane & 15)) * 72 + ts + (lane >> 4) * 8);
            accM = MFMA16(ka, vb, accM);
        }
        float* P = Mf8 + ((size_t)(blockIdx.x & 7) * 4 + (size_t)(r0 >> 12)) * 4096;
        const int rowb = wr * 16 + (lane >> 4) * 4;
        #pragma unroll
        for (int reg = 0; reg < 4; reg++)
            atomicAdd(&P[(rowb + reg) * 64 + wc * 16 + (lane & 15)], accM[reg]);
    }
}

// ---------------------------------------------------------------------------
// K2: out[r][h2] = Q[r][:] @ M_b[:, h2], fp32 out. Sums the 8 Mf copies (L2-hot),
// converts to bf16 fragments in LDS (transposed [h2][h1], stride 72: 16B-aligned).
__global__ __launch_bounds__(256) void qm(
    const unsigned short* __restrict__ Q, const float* __restrict__ Mf8,
    float* __restrict__ out) {
    __shared__ unsigned short Lm[64 * 72];
    const int lane = threadIdx.x & 63, wave = threadIdx.x >> 6;
    const int r0 = blockIdx.x * 64;
    const int b  = r0 >> 12;
    {
        const int tt = threadIdx.x;
        int h1 = tt >> 2, h2c = (tt & 3) * 16;
        const float* Mp = Mf8 + (size_t)b * 4096 + h1 * 64 + h2c;
        float vals[16];
        #pragma unroll
        for (int u = 0; u < 16; u += 4) *(float4*)(vals + u) = *(const float4*)(Mp + u);
        #pragma unroll
        for (int c = 1; c < 8; c++) {
            const float* Mc = Mp + (size_t)c * 16384;   // copy stride = 4*4096 floats
            #pragma unroll
            for (int u = 0; u < 16; u += 4) {
                float4 t = *(const float4*)(Mc + u);
                vals[u] += t.x; vals[u + 1] += t.y; vals[u + 2] += t.z; vals[u + 3] += t.w;
            }
        }
        #pragma unroll
        for (int u = 0; u < 16; u++) Lm[(h2c + u) * 72 + h1] = f2bf(vals[u]);
    }
    __syncthreads();
    const f32x4 z4 = {0.f, 0.f, 0.f, 0.f};
    f32x4 acc[4] = {z4, z4, z4, z4};
    const int rr = r0 + 16 * wave + (lane & 15);
    const int kq = (lane >> 4) * 8;
    #pragma unroll
    for (int ks = 0; ks < 2; ks++) {
        int k0 = ks * 32;
        bf16x8 a = *(const bf16x8*)&Q[(size_t)rr * 64 + k0 + kq];
        #pragma unroll
        for (int nt = 0; nt < 4; nt++) {
            bf16x8 bb = *(const bf16x8*)&Lm[(size_t)(nt * 16 + (lane & 15)) * 72 + k0 + kq];
            acc[nt] = MFMA16(a, bb, acc[nt]);
        }
    }
    const int rowb = r0 + 16 * wave + (lane >> 4) * 4;
    #pragma unroll
    for (int nt = 0; nt < 4; nt++)
        #pragma unroll
        for (int reg = 0; reg < 4; reg++)
            out[(size_t)(rowb + reg) * 64 + nt * 16 + (lane & 15)] = acc[nt][reg];
}

// ---------------------------------------------------------------------------
// Workspace layout:
//   [0, 384K)         WB
//   [1M, 1M+512K)     Mf8 (8 copies x 4 batches x 4096 fp32, zeroed by prep)
//   [2M, 4M)          Q
extern "C" void kernel_launch(void* const* d_in, const int* in_sizes, int n_in,
                              void* d_out, int out_size, void* d_ws, size_t ws_size,
                              hipStream_t stream) {
    const float* idx = (const float*)d_in[0];
    const float* Wq  = (const float*)d_in[1];
    const float* bq  = (const float*)d_in[2];
    const float* Wk  = (const float*)d_in[3];
    const float* bk  = (const float*)d_in[4];
    const float* Wv  = (const float*)d_in[5];
    const float* bv  = (const float*)d_in[6];
    float* out = (float*)d_out;

    char* ws = (char*)d_ws;
    unsigned short* WB  = (unsigned short*)(ws);
    float*          Mf8 = (float*)(ws + (1024u << 10));
    unsigned short* Q   = (unsigned short*)(ws + (2048u << 10));

    hipLaunchKernelGGL(prep,  dim3(96),  dim3(256),  0, stream, Wq, Wk, Wv, WB, Mf8);
    hipLaunchKernelGGL(qkv_m, dim3(256), dim3(1024), 0, stream,
                       idx, WB, bq, bk, bv, Q, Mf8);
    hipLaunchKernelGGL(qm,    dim3(256), dim3(256),  0, stream, Q, Mf8, out);
}